// Round 1
// baseline (377.972 us; speedup 1.0000x reference)
//
#include <hip/hip_runtime.h>

// MHA: out = softmax((XQ Wq^T + bq)(XK Wk^T + bk)^T / sqrt(64)) (XV Wv^T + bv) Wo^T + bo
// B=4, S=2048, D=1024, H=16, Dh=64. All matmuls in bf16 MFMA (16x16x32), fp32 accum.
//
// Pipeline:
//  1) convert fp32 inputs -> bf16 in ws
//  2) Qp = XQ*Wq^T+bq, Kp = XK*Wk^T+bk (bf16 [8192,1024])
//  3) Vt = Wv*XV^T+bv(row)  -> V transposed [1024, 8192] (d-major) for the PV step
//  4) fused flash attention -> AO bf16 [8192,1024]
//  5) d_out = AO*Wo^T+bo (fp32)
//
// Workspace layout (85,983,232 bytes needed):
//  B0: XQ then AO | B1: XK then Vt | B2: XV | B3: Qp | B4: Kp | Wb: 2MB W scratch

#define BATCH 4
#define SEQ   2048
#define NH    16
#define DH    64
#define DM    1024
#define LOG2E 1.4426950408889634f

typedef __attribute__((ext_vector_type(8))) short s16x8;
typedef __attribute__((ext_vector_type(4))) float f32x4;
typedef const __attribute__((address_space(1))) unsigned int* gas1;
typedef __attribute__((address_space(3))) unsigned int* las3;

__device__ __forceinline__ unsigned short f2bf(float f) {
  unsigned int u = __float_as_uint(f);
  u += 0x7FFFu + ((u >> 16) & 1u);   // RTNE
  return (unsigned short)(u >> 16);
}

// ---------------- fp32 -> bf16 ----------------
__global__ __launch_bounds__(256) void cvt_bf16_k(const float* __restrict__ in,
                                                  unsigned short* __restrict__ out, int n4) {
  int i = blockIdx.x * 256 + threadIdx.x;
  if (i < n4) {
    float4 v = ((const float4*)in)[i];
    ushort4 o;
    o.x = f2bf(v.x); o.y = f2bf(v.y); o.z = f2bf(v.z); o.w = f2bf(v.w);
    ((ushort4*)out)[i] = o;
  }
}

// ---------------- GEMM: C[M,N] = A[M,K] * B[N,K]^T + bias ----------------
// 128x128 tile, BK=64, 4 waves (2x2 of 64x64), XOR-swizzled LDS fed by
// global_load_lds with pre-swizzled per-lane global source addresses.
template<bool BIAS_ROW, bool OUT_F32>
__global__ __launch_bounds__(256) void gemm_bt(const unsigned short* __restrict__ A,
                                               const unsigned short* __restrict__ Bm,
                                               const float* __restrict__ bias,
                                               void* __restrict__ Cout,
                                               int M, int N, int K) {
  __shared__ unsigned short As[128 * 64];
  __shared__ unsigned short Bs[128 * 64];
  const int tid = threadIdx.x;
  const int wave = tid >> 6, lane = tid & 63;
  const int lr = lane & 15, lh = lane >> 4;
  const int tM = blockIdx.y, tN = blockIdx.x;
  const int wm = (wave >> 1) * 64, wn = (wave & 1) * 64;
  f32x4 acc[4][4] = {};

  for (int k0 = 0; k0 < K; k0 += 64) {
    __syncthreads();
#pragma unroll
    for (int i = 0; i < 4; ++i) {
      const int slot = wave * 256 + i * 64 + lane;
      const int row = slot >> 3;
      const int cg = (slot & 7) ^ (row & 7);   // inverse-swizzled source chunk
      const unsigned short* ga = A  + (size_t)(tM * 128 + row) * K + k0 + cg * 8;
      const unsigned short* gb = Bm + (size_t)(tN * 128 + row) * K + k0 + cg * 8;
      __builtin_amdgcn_global_load_lds((gas1)ga, (las3)(As + (wave * 256 + i * 64) * 8), 16, 0, 0);
      __builtin_amdgcn_global_load_lds((gas1)gb, (las3)(Bs + (wave * 256 + i * 64) * 8), 16, 0, 0);
    }
    __syncthreads();

    s16x8 af[4][2], bfr[4][2];
#pragma unroll
    for (int mt = 0; mt < 4; ++mt) {
#pragma unroll
      for (int kt = 0; kt < 2; ++kt) {
        const int ra = wm + mt * 16 + lr;
        af[mt][kt] = *(const s16x8*)(As + ra * 64 + (((kt * 4 + lh) ^ (ra & 7)) * 8));
        const int rb = wn + mt * 16 + lr;
        bfr[mt][kt] = *(const s16x8*)(Bs + rb * 64 + (((kt * 4 + lh) ^ (rb & 7)) * 8));
      }
    }
#pragma unroll
    for (int mt = 0; mt < 4; ++mt) {
#pragma unroll
      for (int nt = 0; nt < 4; ++nt) {
        acc[mt][nt] = __builtin_amdgcn_mfma_f32_16x16x32_bf16(af[mt][0], bfr[nt][0], acc[mt][nt], 0, 0, 0);
        acc[mt][nt] = __builtin_amdgcn_mfma_f32_16x16x32_bf16(af[mt][1], bfr[nt][1], acc[mt][nt], 0, 0, 0);
      }
    }
  }

#pragma unroll
  for (int mt = 0; mt < 4; ++mt) {
#pragma unroll
    for (int nt = 0; nt < 4; ++nt) {
      const int row0 = tM * 128 + wm + mt * 16 + lh * 4;
      const int col  = tN * 128 + wn + nt * 16 + lr;
      const float bc = BIAS_ROW ? 0.f : bias[col];
#pragma unroll
      for (int r = 0; r < 4; ++r) {
        const float v = acc[mt][nt][r] + (BIAS_ROW ? bias[row0 + r] : bc);
        if (OUT_F32) ((float*)Cout)[(size_t)(row0 + r) * N + col] = v;
        else ((unsigned short*)Cout)[(size_t)(row0 + r) * N + col] = f2bf(v);
      }
    }
  }
}

// ---------------- fused flash attention ----------------
// grid (S/64, H, B), 256 thr. Wave w owns q-rows [w*16, w*16+16).
// Per KV tile (64): stage K[64,64] and Vt[64(d),64(kv)] to swizzled LDS,
// QK^T (8 mfma/wave), online softmax (16-lane shfl groups), P->LDS, PV (8 mfma).
__global__ __launch_bounds__(256) void attn_k(const unsigned short* __restrict__ Q,
                                              const unsigned short* __restrict__ Kp,
                                              const unsigned short* __restrict__ Vt,
                                              unsigned short* __restrict__ AO) {
  __shared__ unsigned short Ks[64 * 64];
  __shared__ unsigned short Vs[64 * 64];
  __shared__ unsigned short Ps[4 * 16 * 64];
  const int tid = threadIdx.x;
  const int w = tid >> 6, lane = tid & 63;
  const int lr = lane & 15, lh = lane >> 4;
  const int qt = blockIdx.x, h = blockIdx.y, b = blockIdx.z;
  const int qRow = qt * 64 + w * 16 + lr;

  s16x8 qf[2];
#pragma unroll
  for (int kt = 0; kt < 2; ++kt)
    qf[kt] = *(const s16x8*)(Q + (size_t)(b * SEQ + qRow) * DM + h * DH + kt * 32 + lh * 8);

  f32x4 o[4] = {};
  float m_run[4] = {-1e30f, -1e30f, -1e30f, -1e30f};
  float l_run[4] = {0.f, 0.f, 0.f, 0.f};
  unsigned short* Pw = Ps + w * 1024;

  for (int kv0 = 0; kv0 < SEQ; kv0 += 64) {
    __syncthreads();
#pragma unroll
    for (int i = 0; i < 2; ++i) {
      const int slot = w * 128 + i * 64 + lane;
      const int row = slot >> 3;
      const int cg = (slot & 7) ^ (row & 7);
      const unsigned short* gk = Kp + (size_t)(b * SEQ + kv0 + row) * DM + h * DH + cg * 8;
      const unsigned short* gv = Vt + (size_t)(h * DH + row) * (BATCH * SEQ) + b * SEQ + kv0 + cg * 8;
      __builtin_amdgcn_global_load_lds((gas1)gk, (las3)(Ks + (w * 128 + i * 64) * 8), 16, 0, 0);
      __builtin_amdgcn_global_load_lds((gas1)gv, (las3)(Vs + (w * 128 + i * 64) * 8), 16, 0, 0);
    }
    __syncthreads();

    // scores: lane holds S[m=lh*4+r][kv=nt*16+lr] in s[nt][r]
    f32x4 s[4] = {};
#pragma unroll
    for (int nt = 0; nt < 4; ++nt) {
#pragma unroll
      for (int kt = 0; kt < 2; ++kt) {
        const int rk = nt * 16 + lr;
        const s16x8 kf = *(const s16x8*)(Ks + rk * 64 + (((kt * 4 + lh) ^ (rk & 7)) * 8));
        s[nt] = __builtin_amdgcn_mfma_f32_16x16x32_bf16(qf[kt], kf, s[nt], 0, 0, 0);
      }
    }
#pragma unroll
    for (int nt = 0; nt < 4; ++nt) s[nt] *= 0.125f;   // 1/sqrt(64)

    float p[4][4], al[4];
#pragma unroll
    for (int r = 0; r < 4; ++r) {
      float mx = fmaxf(fmaxf(s[0][r], s[1][r]), fmaxf(s[2][r], s[3][r]));
      mx = fmaxf(mx, __shfl_xor(mx, 1));
      mx = fmaxf(mx, __shfl_xor(mx, 2));
      mx = fmaxf(mx, __shfl_xor(mx, 4));
      mx = fmaxf(mx, __shfl_xor(mx, 8));
      const float mn = fmaxf(m_run[r], mx);
      al[r] = exp2f((m_run[r] - mn) * LOG2E);
      m_run[r] = mn;
      float rs = 0.f;
#pragma unroll
      for (int nt = 0; nt < 4; ++nt) {
        const float pv = exp2f((s[nt][r] - mn) * LOG2E);
        p[nt][r] = pv;
        rs += pv;
      }
      rs += __shfl_xor(rs, 1);
      rs += __shfl_xor(rs, 2);
      rs += __shfl_xor(rs, 4);
      rs += __shfl_xor(rs, 8);
      l_run[r] = l_run[r] * al[r] + rs;
    }
    const f32x4 alv = {al[0], al[1], al[2], al[3]};
#pragma unroll
    for (int dt = 0; dt < 4; ++dt) o[dt] *= alv;

    // P -> per-wave swizzled LDS (relayout for A-operand of PV)
#pragma unroll
    for (int nt = 0; nt < 4; ++nt) {
#pragma unroll
      for (int r = 0; r < 4; ++r) {
        const int rp = lh * 4 + r, cp = nt * 16 + lr;
        Pw[rp * 64 + ((((cp >> 3) ^ (rp & 7)) * 8) | (cp & 7))] = f2bf(p[nt][r]);
      }
    }
    // PV: o[dt] += P[16,64] * V[64, dt*16..]
#pragma unroll
    for (int kt = 0; kt < 2; ++kt) {
      const s16x8 pf = *(const s16x8*)(Pw + lr * 64 + (((kt * 4 + lh) ^ (lr & 7)) * 8));
#pragma unroll
      for (int dt = 0; dt < 4; ++dt) {
        const int rv = dt * 16 + lr;
        const s16x8 vf = *(const s16x8*)(Vs + rv * 64 + (((kt * 4 + lh) ^ (rv & 7)) * 8));
        o[dt] = __builtin_amdgcn_mfma_f32_16x16x32_bf16(pf, vf, o[dt], 0, 0, 0);
      }
    }
  }

#pragma unroll
  for (int dt = 0; dt < 4; ++dt) {
#pragma unroll
    for (int r = 0; r < 4; ++r) {
      const int row = qt * 64 + w * 16 + lh * 4 + r;
      const int col = h * DH + dt * 16 + lr;
      AO[(size_t)(b * SEQ + row) * DM + col] = f2bf(o[dt][r] / l_run[r]);
    }
  }
}

extern "C" void kernel_launch(void* const* d_in, const int* in_sizes, int n_in,
                              void* d_out, int out_size, void* d_ws, size_t ws_size,
                              hipStream_t stream) {
  const float* q   = (const float*)d_in[0];
  const float* k   = (const float*)d_in[1];
  const float* v   = (const float*)d_in[2];
  const float* W_q = (const float*)d_in[3];
  const float* b_q = (const float*)d_in[4];
  const float* W_k = (const float*)d_in[5];
  const float* b_k = (const float*)d_in[6];
  const float* W_v = (const float*)d_in[7];
  const float* b_v = (const float*)d_in[8];
  const float* W_o = (const float*)d_in[9];
  const float* b_o = (const float*)d_in[10];

  const size_t SD  = (size_t)BATCH * SEQ * DM;          // 8,388,608 elems
  const size_t SDB = SD * 2;                            // bytes per bf16 buffer
  const size_t D2  = (size_t)DM * DM;                   // 1,048,576 elems
  if (ws_size < 5 * SDB + D2 * 2) return;               // need ~86 MB

  char* base = (char*)d_ws;
  unsigned short* B0 = (unsigned short*)(base);             // XQ -> AO
  unsigned short* B1 = (unsigned short*)(base + 1 * SDB);   // XK -> Vt
  unsigned short* B2 = (unsigned short*)(base + 2 * SDB);   // XV
  unsigned short* B3 = (unsigned short*)(base + 3 * SDB);   // Qp
  unsigned short* B4 = (unsigned short*)(base + 4 * SDB);   // Kp
  unsigned short* Wb = (unsigned short*)(base + 5 * SDB);   // W scratch (2MB)

  const int nSD4 = (int)(SD / 4), nD24 = (int)(D2 / 4);
  const dim3 blk(256);
  const dim3 gP(DM / 128, (BATCH * SEQ) / 128);   // (8, 64)
  const dim3 gV((BATCH * SEQ) / 128, DM / 128);   // (64, 8)
  const dim3 gA(SEQ / 64, NH, BATCH);             // (32, 16, 4)

  // Q projection
  cvt_bf16_k<<<nSD4 / 256, blk, 0, stream>>>(q, B0, nSD4);
  cvt_bf16_k<<<nD24 / 256, blk, 0, stream>>>(W_q, Wb, nD24);
  gemm_bt<false, false><<<gP, blk, 0, stream>>>(B0, Wb, b_q, B3, BATCH * SEQ, DM, DM);
  // K projection
  cvt_bf16_k<<<nSD4 / 256, blk, 0, stream>>>(k, B1, nSD4);
  cvt_bf16_k<<<nD24 / 256, blk, 0, stream>>>(W_k, Wb, nD24);
  gemm_bt<false, false><<<gP, blk, 0, stream>>>(B1, Wb, b_k, B4, BATCH * SEQ, DM, DM);
  // V projection, transposed output: Vt[d, b*S+s] = (W_v XV^T)[d, i] + b_v[d]
  cvt_bf16_k<<<nSD4 / 256, blk, 0, stream>>>(v, B2, nSD4);
  cvt_bf16_k<<<nD24 / 256, blk, 0, stream>>>(W_v, Wb, nD24);
  gemm_bt<true, false><<<gV, blk, 0, stream>>>(Wb, B2, b_v, B1, DM, BATCH * SEQ, DM);
  // fused attention
  attn_k<<<gA, blk, 0, stream>>>(B3, B4, B1, B0);
  // output projection -> fp32
  cvt_bf16_k<<<nD24 / 256, blk, 0, stream>>>(W_o, Wb, nD24);
  gemm_bt<false, true><<<gP, blk, 0, stream>>>(B0, Wb, b_o, d_out, BATCH * SEQ, DM, DM);
}

// Round 2
// 255.014 us; speedup vs baseline: 1.4822x; 1.4822x over previous
//
#include <hip/hip_runtime.h>

// MHA: out = softmax((XQ Wq^T + bq)(XK Wk^T + bk)^T / sqrt(64)) (XV Wv^T + bv) Wo^T + bo
// B=4, S=2048, D=1024, H=16, Dh=64. All matmuls in bf16 MFMA (16x16x32), fp32 accum.
//
// Attention kernel (v2): swapped QK^T (lane-local softmax), QBLK=32/wave,
// O^T accumulation (lane-local m/l/rescale), cvt_pk P-repack through swizzled
// per-wave LDS, defer-max rescale, XCD-aware block swizzle.

#define BATCH 4
#define SEQ   2048
#define NH    16
#define DH    64
#define DM    1024
#define LOG2E 1.4426950408889634f
#define CSC   (0.125f * LOG2E)   // softmax scale folded into exp2 domain

typedef __attribute__((ext_vector_type(8))) short s16x8;
typedef __attribute__((ext_vector_type(4))) float f32x4;
typedef const __attribute__((address_space(1))) unsigned int* gas1;
typedef __attribute__((address_space(3))) unsigned int* las3;

__device__ __forceinline__ unsigned short f2bf(float f) {
  unsigned int u = __float_as_uint(f);
  u += 0x7FFFu + ((u >> 16) & 1u);   // RTNE
  return (unsigned short)(u >> 16);
}

__device__ __forceinline__ unsigned int cvt_pk_bf16(float lo, float hi) {
  unsigned int r;
  asm("v_cvt_pk_bf16_f32 %0, %1, %2" : "=v"(r) : "v"(lo), "v"(hi));
  return r;
}

// ---------------- fp32 -> bf16 ----------------
__global__ __launch_bounds__(256) void cvt_bf16_k(const float* __restrict__ in,
                                                  unsigned short* __restrict__ out, int n4) {
  int i = blockIdx.x * 256 + threadIdx.x;
  if (i < n4) {
    float4 v = ((const float4*)in)[i];
    ushort4 o;
    o.x = f2bf(v.x); o.y = f2bf(v.y); o.z = f2bf(v.z); o.w = f2bf(v.w);
    ((ushort4*)out)[i] = o;
  }
}

// ---------------- GEMM: C[M,N] = A[M,K] * B[N,K]^T + bias ----------------
template<bool BIAS_ROW, bool OUT_F32>
__global__ __launch_bounds__(256) void gemm_bt(const unsigned short* __restrict__ A,
                                               const unsigned short* __restrict__ Bm,
                                               const float* __restrict__ bias,
                                               void* __restrict__ Cout,
                                               int M, int N, int K) {
  __shared__ unsigned short As[128 * 64];
  __shared__ unsigned short Bs[128 * 64];
  const int tid = threadIdx.x;
  const int wave = tid >> 6, lane = tid & 63;
  const int lr = lane & 15, lh = lane >> 4;
  const int tM = blockIdx.y, tN = blockIdx.x;
  const int wm = (wave >> 1) * 64, wn = (wave & 1) * 64;
  f32x4 acc[4][4] = {};

  for (int k0 = 0; k0 < K; k0 += 64) {
    __syncthreads();
#pragma unroll
    for (int i = 0; i < 4; ++i) {
      const int slot = wave * 256 + i * 64 + lane;
      const int row = slot >> 3;
      const int cg = (slot & 7) ^ (row & 7);   // inverse-swizzled source chunk
      const unsigned short* ga = A  + (size_t)(tM * 128 + row) * K + k0 + cg * 8;
      const unsigned short* gb = Bm + (size_t)(tN * 128 + row) * K + k0 + cg * 8;
      __builtin_amdgcn_global_load_lds((gas1)ga, (las3)(As + (wave * 256 + i * 64) * 8), 16, 0, 0);
      __builtin_amdgcn_global_load_lds((gas1)gb, (las3)(Bs + (wave * 256 + i * 64) * 8), 16, 0, 0);
    }
    __syncthreads();

    s16x8 af[4][2], bfr[4][2];
#pragma unroll
    for (int mt = 0; mt < 4; ++mt) {
#pragma unroll
      for (int kt = 0; kt < 2; ++kt) {
        const int ra = wm + mt * 16 + lr;
        af[mt][kt] = *(const s16x8*)(As + ra * 64 + (((kt * 4 + lh) ^ (ra & 7)) * 8));
        const int rb = wn + mt * 16 + lr;
        bfr[mt][kt] = *(const s16x8*)(Bs + rb * 64 + (((kt * 4 + lh) ^ (rb & 7)) * 8));
      }
    }
#pragma unroll
    for (int mt = 0; mt < 4; ++mt) {
#pragma unroll
      for (int nt = 0; nt < 4; ++nt) {
        acc[mt][nt] = __builtin_amdgcn_mfma_f32_16x16x32_bf16(af[mt][0], bfr[nt][0], acc[mt][nt], 0, 0, 0);
        acc[mt][nt] = __builtin_amdgcn_mfma_f32_16x16x32_bf16(af[mt][1], bfr[nt][1], acc[mt][nt], 0, 0, 0);
      }
    }
  }

#pragma unroll
  for (int mt = 0; mt < 4; ++mt) {
#pragma unroll
    for (int nt = 0; nt < 4; ++nt) {
      const int row0 = tM * 128 + wm + mt * 16 + lh * 4;
      const int col  = tN * 128 + wn + nt * 16 + lr;
      const float bc = BIAS_ROW ? 0.f : bias[col];
#pragma unroll
      for (int r = 0; r < 4; ++r) {
        const float v = acc[mt][nt][r] + (BIAS_ROW ? bias[row0 + r] : bc);
        if (OUT_F32) ((float*)Cout)[(size_t)(row0 + r) * N + col] = v;
        else ((unsigned short*)Cout)[(size_t)(row0 + r) * N + col] = f2bf(v);
      }
    }
  }
}

// ---------------- fused flash attention v2 ----------------
// 1D grid 1024 (XCD-swizzled -> qt, h, b), 256 thr = 4 waves, QBLK=32/wave.
// Swapped QK^T: s[qb][nt][r] = S[kv=nt*16+lh*4+r][q=qb*16+lr]; lane-local
// softmax (2 shfl per reduce). P repacked via cvt_pk -> swizzled per-wave LDS
// -> PV B-frags. O accumulated transposed: o[qb][dt][r] = O[q=lr][d=dt*16+lh*4+r].
__global__ __launch_bounds__(256) void attn_k(const unsigned short* __restrict__ Q,
                                              const unsigned short* __restrict__ Kp,
                                              const unsigned short* __restrict__ Vt,
                                              unsigned short* __restrict__ AO) {
  __shared__ unsigned short Ks[64 * 64];        // [kv][d]   8KB, chunk^row&7 swizzle
  __shared__ unsigned short Vs[64 * 64];        // [d][kv]   8KB, chunk^row&7 swizzle
  __shared__ unsigned short Ps[4 * 32 * 64];    // per-wave [q 32][kv 64], 16KB
  const int tid = threadIdx.x;
  const int w = tid >> 6, lane = tid & 63;
  const int lr = lane & 15, lh = lane >> 4;
  const int sw = lr & 7;                        // row-swizzle key (all read rows = x*16+lr)

  // XCD-aware swizzle: 8 consecutive (b,h) pairs per XCD (per-XCD KV set ~4MB = L2)
  const int id = blockIdx.x;                    // 0..1023
  const int g  = (id & 7) * 128 + (id >> 3);    // bijective (1024 % 8 == 0)
  const int qt = g & 15;
  const int hb = g >> 4;
  const int h = hb & 15, b = hb >> 4;

  s16x8 qf[2][2];
#pragma unroll
  for (int qb = 0; qb < 2; ++qb)
#pragma unroll
    for (int kt = 0; kt < 2; ++kt)
      qf[qb][kt] = *(const s16x8*)(Q + (size_t)(b * SEQ + qt * 128 + w * 32 + qb * 16 + lr) * DM
                                     + h * DH + kt * 32 + lh * 8);

  f32x4 o[2][4] = {};
  float m_run[2] = {-1e30f, -1e30f};
  float l_run[2] = {0.f, 0.f};
  unsigned short* Pw = Ps + w * 2048;

  for (int kv0 = 0; kv0 < SEQ; kv0 += 64) {
    __syncthreads();
#pragma unroll
    for (int i = 0; i < 2; ++i) {
      const int slot = i * 256 + w * 64 + lane;
      const int row = slot >> 3;
      const int cg = (slot & 7) ^ (row & 7);
      const unsigned short* gk = Kp + (size_t)(b * SEQ + kv0 + row) * DM + h * DH + cg * 8;
      const unsigned short* gv = Vt + (size_t)(h * DH + row) * (BATCH * SEQ) + b * SEQ + kv0 + cg * 8;
      __builtin_amdgcn_global_load_lds((gas1)gk, (las3)(Ks + (i * 256 + w * 64) * 8), 16, 0, 0);
      __builtin_amdgcn_global_load_lds((gas1)gv, (las3)(Vs + (i * 256 + w * 64) * 8), 16, 0, 0);
    }
    __syncthreads();

    // QK^T (swapped operands): rows of output = kv, cols = q
    f32x4 s[2][4] = {};
#pragma unroll
    for (int nt = 0; nt < 4; ++nt) {
#pragma unroll
      for (int kt = 0; kt < 2; ++kt) {
        const s16x8 kf = *(const s16x8*)(Ks + (nt * 16 + lr) * 64 + (((kt * 4 + lh) ^ sw) * 8));
        s[0][nt] = __builtin_amdgcn_mfma_f32_16x16x32_bf16(kf, qf[0][kt], s[0][nt], 0, 0, 0);
        s[1][nt] = __builtin_amdgcn_mfma_f32_16x16x32_bf16(kf, qf[1][kt], s[1][nt], 0, 0, 0);
      }
    }

    // online softmax, lane-local (q = lr), defer-max rescale
#pragma unroll
    for (int qb = 0; qb < 2; ++qb) {
      float mx = fmaxf(fmaxf(s[qb][0][0], s[qb][0][1]), fmaxf(s[qb][0][2], s[qb][0][3]));
#pragma unroll
      for (int nt = 1; nt < 4; ++nt)
        mx = fmaxf(mx, fmaxf(fmaxf(s[qb][nt][0], s[qb][nt][1]),
                             fmaxf(s[qb][nt][2], s[qb][nt][3])));
      mx = fmaxf(mx, __shfl_xor(mx, 16));
      mx = fmaxf(mx, __shfl_xor(mx, 32));
      if (!__all(mx - m_run[qb] <= 64.0f)) {   // 64 raw = 8 in exp-arg domain
        const float al = __builtin_amdgcn_exp2f((m_run[qb] - mx) * CSC);
        m_run[qb] = mx;
        l_run[qb] *= al;
#pragma unroll
        for (int dt = 0; dt < 4; ++dt) o[qb][dt] *= al;
      }
      const float base = m_run[qb] * CSC;
      float p[4][4];
      float rs = 0.f;
#pragma unroll
      for (int nt = 0; nt < 4; ++nt)
#pragma unroll
        for (int r = 0; r < 4; ++r) {
          p[nt][r] = __builtin_amdgcn_exp2f(s[qb][nt][r] * CSC - base);
          rs += p[nt][r];
        }
      rs += __shfl_xor(rs, 16);
      rs += __shfl_xor(rs, 32);
      l_run[qb] += rs;

      // pack P -> per-wave swizzled LDS (rows q, cols kv)
      const int qrow = qb * 16 + lr;
#pragma unroll
      for (int nt = 0; nt < 4; ++nt) {
        uint2 wd;
        wd.x = cvt_pk_bf16(p[nt][0], p[nt][1]);
        wd.y = cvt_pk_bf16(p[nt][2], p[nt][3]);
        const int c8 = nt * 2 + (lh >> 1);
        *(uint2*)(Pw + qrow * 64 + (((c8 ^ sw) << 3) | ((lh & 1) << 2))) = wd;
      }
    }

    // PV: o[qb][dt] += V^T-frag x P-frag  (output rows = d, cols = q)
#pragma unroll
    for (int nb = 0; nb < 2; ++nb) {
      const s16x8 pf0 = *(const s16x8*)(Pw + lr * 64        + (((nb * 4 + lh) ^ sw) * 8));
      const s16x8 pf1 = *(const s16x8*)(Pw + (16 + lr) * 64 + (((nb * 4 + lh) ^ sw) * 8));
#pragma unroll
      for (int dt = 0; dt < 4; ++dt) {
        const s16x8 vf = *(const s16x8*)(Vs + (dt * 16 + lr) * 64 + (((nb * 4 + lh) ^ sw) * 8));
        o[0][dt] = __builtin_amdgcn_mfma_f32_16x16x32_bf16(vf, pf0, o[0][dt], 0, 0, 0);
        o[1][dt] = __builtin_amdgcn_mfma_f32_16x16x32_bf16(vf, pf1, o[1][dt], 0, 0, 0);
      }
    }
  }

  // epilogue: normalize, pack pairs, store (O[q=lr][d])
#pragma unroll
  for (int qb = 0; qb < 2; ++qb) {
    const float rl = __builtin_amdgcn_rcpf(l_run[qb]);
    unsigned short* orow = AO + (size_t)(b * SEQ + qt * 128 + w * 32 + qb * 16 + lr) * DM + h * DH;
#pragma unroll
    for (int dt = 0; dt < 4; ++dt) {
      *(unsigned int*)(orow + dt * 16 + lh * 4)     = cvt_pk_bf16(o[qb][dt][0] * rl, o[qb][dt][1] * rl);
      *(unsigned int*)(orow + dt * 16 + lh * 4 + 2) = cvt_pk_bf16(o[qb][dt][2] * rl, o[qb][dt][3] * rl);
    }
  }
}

extern "C" void kernel_launch(void* const* d_in, const int* in_sizes, int n_in,
                              void* d_out, int out_size, void* d_ws, size_t ws_size,
                              hipStream_t stream) {
  const float* q   = (const float*)d_in[0];
  const float* k   = (const float*)d_in[1];
  const float* v   = (const float*)d_in[2];
  const float* W_q = (const float*)d_in[3];
  const float* b_q = (const float*)d_in[4];
  const float* W_k = (const float*)d_in[5];
  const float* b_k = (const float*)d_in[6];
  const float* W_v = (const float*)d_in[7];
  const float* b_v = (const float*)d_in[8];
  const float* W_o = (const float*)d_in[9];
  const float* b_o = (const float*)d_in[10];

  const size_t SD  = (size_t)BATCH * SEQ * DM;          // 8,388,608 elems
  const size_t SDB = SD * 2;                            // bytes per bf16 buffer
  const size_t D2  = (size_t)DM * DM;                   // 1,048,576 elems
  if (ws_size < 5 * SDB + D2 * 2) return;               // need ~86 MB

  char* base = (char*)d_ws;
  unsigned short* B0 = (unsigned short*)(base);             // XQ -> AO
  unsigned short* B1 = (unsigned short*)(base + 1 * SDB);   // XK -> Vt
  unsigned short* B2 = (unsigned short*)(base + 2 * SDB);   // XV
  unsigned short* B3 = (unsigned short*)(base + 3 * SDB);   // Qp
  unsigned short* B4 = (unsigned short*)(base + 4 * SDB);   // Kp
  unsigned short* Wb = (unsigned short*)(base + 5 * SDB);   // W scratch (2MB)

  const int nSD4 = (int)(SD / 4), nD24 = (int)(D2 / 4);
  const dim3 blk(256);
  const dim3 gP(DM / 128, (BATCH * SEQ) / 128);   // (8, 64)
  const dim3 gV((BATCH * SEQ) / 128, DM / 128);   // (64, 8)
  const dim3 gA(16 * NH * BATCH);                 // 1024, XCD-swizzled in-kernel

  // Q projection
  cvt_bf16_k<<<nSD4 / 256, blk, 0, stream>>>(q, B0, nSD4);
  cvt_bf16_k<<<nD24 / 256, blk, 0, stream>>>(W_q, Wb, nD24);
  gemm_bt<false, false><<<gP, blk, 0, stream>>>(B0, Wb, b_q, B3, BATCH * SEQ, DM, DM);
  // K projection
  cvt_bf16_k<<<nSD4 / 256, blk, 0, stream>>>(k, B1, nSD4);
  cvt_bf16_k<<<nD24 / 256, blk, 0, stream>>>(W_k, Wb, nD24);
  gemm_bt<false, false><<<gP, blk, 0, stream>>>(B1, Wb, b_k, B4, BATCH * SEQ, DM, DM);
  // V projection, transposed output: Vt[d, b*S+s] = (W_v XV^T)[d, i] + b_v[d]
  cvt_bf16_k<<<nSD4 / 256, blk, 0, stream>>>(v, B2, nSD4);
  cvt_bf16_k<<<nD24 / 256, blk, 0, stream>>>(W_v, Wb, nD24);
  gemm_bt<true, false><<<gV, blk, 0, stream>>>(Wb, B2, b_v, B1, DM, BATCH * SEQ, DM);
  // fused attention
  attn_k<<<gA, blk, 0, stream>>>(B3, B4, B1, B0);
  // output projection -> fp32
  cvt_bf16_k<<<nD24 / 256, blk, 0, stream>>>(W_o, Wb, nD24);
  gemm_bt<false, true><<<gP, blk, 0, stream>>>(B0, Wb, b_o, d_out, BATCH * SEQ, DM, DM);
}

// Round 3
// 244.441 us; speedup vs baseline: 1.5463x; 1.0433x over previous
//
#include <hip/hip_runtime.h>

// MHA: out = softmax((XQ Wq^T + bq)(XK Wk^T + bk)^T / sqrt(64)) (XV Wv^T + bv) Wo^T + bo
// B=4, S=2048, D=1024, H=16, Dh=64. All matmuls bf16 MFMA 16x16x32, fp32 accum.
//
// v3: attn uses 2-phase double-buffered K/V staging (raw s_barrier + counted
// vmcnt — no full drains); 6 launches total (cvt x3 fused, cvt W x4 fused
// with bf16 W_q/W_k/W_v parked in d_out scratch, Q+K GEMMs merged via grid.z).

#define BATCH 4
#define SEQ   2048
#define NH    16
#define DH    64
#define DM    1024
#define LOG2E 1.4426950408889634f
#define CSC   (0.125f * LOG2E)   // softmax scale folded into exp2 domain

typedef __attribute__((ext_vector_type(8))) short s16x8;
typedef __attribute__((ext_vector_type(4))) float f32x4;
typedef const __attribute__((address_space(1))) unsigned int* gas1;
typedef __attribute__((address_space(3))) unsigned int* las3;

__device__ __forceinline__ unsigned short f2bf(float f) {
  unsigned int u = __float_as_uint(f);
  u += 0x7FFFu + ((u >> 16) & 1u);   // RTNE
  return (unsigned short)(u >> 16);
}

__device__ __forceinline__ unsigned int cvt_pk_bf16(float lo, float hi) {
  unsigned int r;
  asm("v_cvt_pk_bf16_f32 %0, %1, %2" : "=v"(r) : "v"(lo), "v"(hi));
  return r;
}

// ---------------- fp32 -> bf16, 3 tensors in one launch ----------------
__global__ __launch_bounds__(256) void cvt3_k(const float* __restrict__ s0,
                                              const float* __restrict__ s1,
                                              const float* __restrict__ s2,
                                              unsigned short* __restrict__ d0,
                                              unsigned short* __restrict__ d1,
                                              unsigned short* __restrict__ d2, int n4) {
  const float* s = blockIdx.y == 0 ? s0 : blockIdx.y == 1 ? s1 : s2;
  unsigned short* d = blockIdx.y == 0 ? d0 : blockIdx.y == 1 ? d1 : d2;
  int i = blockIdx.x * 256 + threadIdx.x;
  if (i < n4) {
    float4 v = ((const float4*)s)[i];
    ushort4 o;
    o.x = f2bf(v.x); o.y = f2bf(v.y); o.z = f2bf(v.z); o.w = f2bf(v.w);
    ((ushort4*)d)[i] = o;
  }
}

// ---------------- fp32 -> bf16, 4 weight matrices in one launch ----------------
__global__ __launch_bounds__(256) void cvt4_k(const float* __restrict__ s0,
                                              const float* __restrict__ s1,
                                              const float* __restrict__ s2,
                                              const float* __restrict__ s3,
                                              unsigned short* __restrict__ d0,
                                              unsigned short* __restrict__ d1,
                                              unsigned short* __restrict__ d2,
                                              unsigned short* __restrict__ d3, int n4) {
  const float* s = blockIdx.y == 0 ? s0 : blockIdx.y == 1 ? s1 : blockIdx.y == 2 ? s2 : s3;
  unsigned short* d = blockIdx.y == 0 ? d0 : blockIdx.y == 1 ? d1 : blockIdx.y == 2 ? d2 : d3;
  int i = blockIdx.x * 256 + threadIdx.x;
  if (i < n4) {
    float4 v = ((const float4*)s)[i];
    ushort4 o;
    o.x = f2bf(v.x); o.y = f2bf(v.y); o.z = f2bf(v.z); o.w = f2bf(v.w);
    ((ushort4*)d)[i] = o;
  }
}

// ---------------- GEMM core: C[M,N] = A[M,K] * B[N,K]^T + bias ----------------
// 128x128 tile, BK=64, 4 waves (2x2 of 64x64), XOR-swizzled LDS fed by
// global_load_lds with pre-swizzled per-lane global source addresses.
template<bool BIAS_ROW, bool OUT_F32>
__device__ __forceinline__ void gemm_core(const unsigned short* __restrict__ A,
                                          const unsigned short* __restrict__ Bm,
                                          const float* __restrict__ bias,
                                          void* __restrict__ Cout,
                                          int M, int N, int K, int tM, int tN,
                                          unsigned short* As, unsigned short* Bs) {
  const int tid = threadIdx.x;
  const int wave = tid >> 6, lane = tid & 63;
  const int lr = lane & 15, lh = lane >> 4;
  const int wm = (wave >> 1) * 64, wn = (wave & 1) * 64;
  f32x4 acc[4][4] = {};

  for (int k0 = 0; k0 < K; k0 += 64) {
    __syncthreads();
#pragma unroll
    for (int i = 0; i < 4; ++i) {
      const int slot = wave * 256 + i * 64 + lane;
      const int row = slot >> 3;
      const int cg = (slot & 7) ^ (row & 7);   // inverse-swizzled source chunk
      const unsigned short* ga = A  + (size_t)(tM * 128 + row) * K + k0 + cg * 8;
      const unsigned short* gb = Bm + (size_t)(tN * 128 + row) * K + k0 + cg * 8;
      __builtin_amdgcn_global_load_lds((gas1)ga, (las3)(As + (wave * 256 + i * 64) * 8), 16, 0, 0);
      __builtin_amdgcn_global_load_lds((gas1)gb, (las3)(Bs + (wave * 256 + i * 64) * 8), 16, 0, 0);
    }
    __syncthreads();

    s16x8 af[4][2], bfr[4][2];
#pragma unroll
    for (int mt = 0; mt < 4; ++mt) {
#pragma unroll
      for (int kt = 0; kt < 2; ++kt) {
        const int ra = wm + mt * 16 + lr;
        af[mt][kt] = *(const s16x8*)(As + ra * 64 + (((kt * 4 + lh) ^ (ra & 7)) * 8));
        const int rb = wn + mt * 16 + lr;
        bfr[mt][kt] = *(const s16x8*)(Bs + rb * 64 + (((kt * 4 + lh) ^ (rb & 7)) * 8));
      }
    }
#pragma unroll
    for (int mt = 0; mt < 4; ++mt) {
#pragma unroll
      for (int nt = 0; nt < 4; ++nt) {
        acc[mt][nt] = __builtin_amdgcn_mfma_f32_16x16x32_bf16(af[mt][0], bfr[nt][0], acc[mt][nt], 0, 0, 0);
        acc[mt][nt] = __builtin_amdgcn_mfma_f32_16x16x32_bf16(af[mt][1], bfr[nt][1], acc[mt][nt], 0, 0, 0);
      }
    }
  }

#pragma unroll
  for (int mt = 0; mt < 4; ++mt) {
#pragma unroll
    for (int nt = 0; nt < 4; ++nt) {
      const int row0 = tM * 128 + wm + mt * 16 + lh * 4;
      const int col  = tN * 128 + wn + nt * 16 + lr;
      const float bc = BIAS_ROW ? 0.f : bias[col];
#pragma unroll
      for (int r = 0; r < 4; ++r) {
        const float v = acc[mt][nt][r] + (BIAS_ROW ? bias[row0 + r] : bc);
        if (OUT_F32) ((float*)Cout)[(size_t)(row0 + r) * N + col] = v;
        else ((unsigned short*)Cout)[(size_t)(row0 + r) * N + col] = f2bf(v);
      }
    }
  }
}

template<bool BIAS_ROW, bool OUT_F32>
__global__ __launch_bounds__(256) void gemm_bt(const unsigned short* __restrict__ A,
                                               const unsigned short* __restrict__ Bm,
                                               const float* __restrict__ bias,
                                               void* __restrict__ Cout, int M, int N, int K) {
  __shared__ unsigned short As[128 * 64];
  __shared__ unsigned short Bs[128 * 64];
  gemm_core<BIAS_ROW, OUT_F32>(A, Bm, bias, Cout, M, N, K, blockIdx.y, blockIdx.x, As, Bs);
}

// Q and K projections merged: blockIdx.z selects the operand set.
__global__ __launch_bounds__(256) void gemm_qk(const unsigned short* __restrict__ A0,
                                               const unsigned short* __restrict__ A1,
                                               const unsigned short* __restrict__ W0,
                                               const unsigned short* __restrict__ W1,
                                               const float* __restrict__ c0,
                                               const float* __restrict__ c1,
                                               void* __restrict__ C0, void* __restrict__ C1,
                                               int M, int N, int K) {
  __shared__ unsigned short As[128 * 64];
  __shared__ unsigned short Bs[128 * 64];
  if (blockIdx.z == 0)
    gemm_core<false, false>(A0, W0, c0, C0, M, N, K, blockIdx.y, blockIdx.x, As, Bs);
  else
    gemm_core<false, false>(A1, W1, c1, C1, M, N, K, blockIdx.y, blockIdx.x, As, Bs);
}

// ---------------- fused flash attention v3 ----------------
// 1D grid 1024 (XCD-swizzled), 256 thr = 4 waves, QBLK=32/wave, KVBLK=64.
// 2-phase double-buffered K/V staging: STAGE(t+1) issued before compute(t);
// raw s_barrier + counted vmcnt(4) — next tile's loads stay in flight.
__global__ __launch_bounds__(256) void attn_k(const unsigned short* __restrict__ Q,
                                              const unsigned short* __restrict__ Kp,
                                              const unsigned short* __restrict__ Vt,
                                              unsigned short* __restrict__ AO) {
  __shared__ unsigned short Ks[2][64 * 64];     // [kv][d]  2 x 8KB
  __shared__ unsigned short Vs[2][64 * 64];     // [d][kv]  2 x 8KB
  __shared__ unsigned short Ps[4 * 32 * 64];    // per-wave [q 32][kv 64], 16KB
  const int tid = threadIdx.x;
  const int w = tid >> 6, lane = tid & 63;
  const int lr = lane & 15, lh = lane >> 4;
  const int sw = lr & 7;

  // XCD-aware swizzle: 8 consecutive (b,h) pairs per XCD (per-XCD KV ~4MB = L2)
  const int id = blockIdx.x;                    // 0..1023
  const int g  = (id & 7) * 128 + (id >> 3);    // bijective (1024 % 8 == 0)
  const int qt = g & 15;
  const int hb = g >> 4;
  const int h = hb & 15, b = hb >> 4;

  s16x8 qf[2][2];
#pragma unroll
  for (int qb = 0; qb < 2; ++qb)
#pragma unroll
    for (int kt = 0; kt < 2; ++kt)
      qf[qb][kt] = *(const s16x8*)(Q + (size_t)(b * SEQ + qt * 128 + w * 32 + qb * 16 + lr) * DM
                                     + h * DH + kt * 32 + lh * 8);
  asm volatile("s_waitcnt vmcnt(0)" ::: "memory");   // qf resident; vmcnt accounting clean
  __builtin_amdgcn_sched_barrier(0);

  f32x4 o[2][4] = {};
  float m_run[2] = {-1e30f, -1e30f};
  float l_run[2] = {0.f, 0.f};
  unsigned short* Pw = Ps + w * 2048;

  const unsigned short* Kbase = Kp + (size_t)b * SEQ * DM + h * DH;
  const unsigned short* Vbase = Vt + (size_t)h * DH * (BATCH * SEQ) + (size_t)b * SEQ;

  auto stage = [&](int buf, int kv0) {
#pragma unroll
    for (int i = 0; i < 2; ++i) {
      const int slot = i * 256 + w * 64 + lane;
      const int row = slot >> 3;
      const int cg = (slot & 7) ^ (row & 7);
      const unsigned short* gk = Kbase + (size_t)(kv0 + row) * DM + cg * 8;
      const unsigned short* gv = Vbase + (size_t)row * (BATCH * SEQ) + kv0 + cg * 8;
      __builtin_amdgcn_global_load_lds((gas1)gk, (las3)(&Ks[buf][(i * 256 + w * 64) * 8]), 16, 0, 0);
      __builtin_amdgcn_global_load_lds((gas1)gv, (las3)(&Vs[buf][(i * 256 + w * 64) * 8]), 16, 0, 0);
    }
  };

  stage(0, 0);
  for (int t = 0; t < 32; ++t) {
    const int cur = t & 1;
    if (t < 31) {
      stage(cur ^ 1, (t + 1) * 64);                     // prefetch next tile
      asm volatile("s_waitcnt vmcnt(4)" ::: "memory");  // cur's 4 loads done; next 4 in flight
    } else {
      asm volatile("s_waitcnt vmcnt(0)" ::: "memory");
    }
    __builtin_amdgcn_s_barrier();
    __builtin_amdgcn_sched_barrier(0);
    const unsigned short* Kc = Ks[cur];
    const unsigned short* Vc = Vs[cur];

    // QK^T (swapped operands): rows = kv, cols = q
    f32x4 s[2][4] = {};
#pragma unroll
    for (int nt = 0; nt < 4; ++nt) {
#pragma unroll
      for (int kt = 0; kt < 2; ++kt) {
        const s16x8 kf = *(const s16x8*)(Kc + (nt * 16 + lr) * 64 + (((kt * 4 + lh) ^ sw) * 8));
        s[0][nt] = __builtin_amdgcn_mfma_f32_16x16x32_bf16(kf, qf[0][kt], s[0][nt], 0, 0, 0);
        s[1][nt] = __builtin_amdgcn_mfma_f32_16x16x32_bf16(kf, qf[1][kt], s[1][nt], 0, 0, 0);
      }
    }

    // online softmax, lane-local (q = lr), defer-max rescale
#pragma unroll
    for (int qb = 0; qb < 2; ++qb) {
      float mx = fmaxf(fmaxf(s[qb][0][0], s[qb][0][1]), fmaxf(s[qb][0][2], s[qb][0][3]));
#pragma unroll
      for (int nt = 1; nt < 4; ++nt)
        mx = fmaxf(mx, fmaxf(fmaxf(s[qb][nt][0], s[qb][nt][1]),
                             fmaxf(s[qb][nt][2], s[qb][nt][3])));
      mx = fmaxf(mx, __shfl_xor(mx, 16));
      mx = fmaxf(mx, __shfl_xor(mx, 32));
      if (!__all(mx - m_run[qb] <= 64.0f)) {   // 64 raw = 8 in exp-arg domain
        const float al = __builtin_amdgcn_exp2f((m_run[qb] - mx) * CSC);
        m_run[qb] = mx;
        l_run[qb] *= al;
#pragma unroll
        for (int dt = 0; dt < 4; ++dt) o[qb][dt] *= al;
      }
      const float base = m_run[qb] * CSC;
      float p[4][4];
      float rs = 0.f;
#pragma unroll
      for (int nt = 0; nt < 4; ++nt)
#pragma unroll
        for (int r = 0; r < 4; ++r) {
          p[nt][r] = __builtin_amdgcn_exp2f(s[qb][nt][r] * CSC - base);
          rs += p[nt][r];
        }
      rs += __shfl_xor(rs, 16);
      rs += __shfl_xor(rs, 32);
      l_run[qb] += rs;

      // pack P -> per-wave swizzled LDS (rows q, cols kv)
      const int qrow = qb * 16 + lr;
#pragma unroll
      for (int nt = 0; nt < 4; ++nt) {
        uint2 wd;
        wd.x = cvt_pk_bf16(p[nt][0], p[nt][1]);
        wd.y = cvt_pk_bf16(p[nt][2], p[nt][3]);
        const int c8 = nt * 2 + (lh >> 1);
        *(uint2*)(Pw + qrow * 64 + (((c8 ^ sw) << 3) | ((lh & 1) << 2))) = wd;
      }
    }

    // PV: o[qb][dt] += V-frag x P-frag  (rows = d, cols = q)
#pragma unroll
    for (int nb = 0; nb < 2; ++nb) {
      const s16x8 pf0 = *(const s16x8*)(Pw + lr * 64        + (((nb * 4 + lh) ^ sw) * 8));
      const s16x8 pf1 = *(const s16x8*)(Pw + (16 + lr) * 64 + (((nb * 4 + lh) ^ sw) * 8));
#pragma unroll
      for (int dt = 0; dt < 4; ++dt) {
        const s16x8 vf = *(const s16x8*)(Vc + (dt * 16 + lr) * 64 + (((nb * 4 + lh) ^ sw) * 8));
        o[0][dt] = __builtin_amdgcn_mfma_f32_16x16x32_bf16(vf, pf0, o[0][dt], 0, 0, 0);
        o[1][dt] = __builtin_amdgcn_mfma_f32_16x16x32_bf16(vf, pf1, o[1][dt], 0, 0, 0);
      }
    }
    __builtin_amdgcn_sched_barrier(0);
    __builtin_amdgcn_s_barrier();   // all waves done reading buf[cur] before it's restaged
  }

  // epilogue: normalize, pack pairs, store (O[q=lr][d])
#pragma unroll
  for (int qb = 0; qb < 2; ++qb) {
    const float rl = __builtin_amdgcn_rcpf(l_run[qb]);
    unsigned short* orow = AO + (size_t)(b * SEQ + qt * 128 + w * 32 + qb * 16 + lr) * DM + h * DH;
#pragma unroll
    for (int dt = 0; dt < 4; ++dt) {
      *(unsigned int*)(orow + dt * 16 + lh * 4)     = cvt_pk_bf16(o[qb][dt][0] * rl, o[qb][dt][1] * rl);
      *(unsigned int*)(orow + dt * 16 + lh * 4 + 2) = cvt_pk_bf16(o[qb][dt][2] * rl, o[qb][dt][3] * rl);
    }
  }
}

extern "C" void kernel_launch(void* const* d_in, const int* in_sizes, int n_in,
                              void* d_out, int out_size, void* d_ws, size_t ws_size,
                              hipStream_t stream) {
  const float* q   = (const float*)d_in[0];
  const float* k   = (const float*)d_in[1];
  const float* v   = (const float*)d_in[2];
  const float* W_q = (const float*)d_in[3];
  const float* b_q = (const float*)d_in[4];
  const float* W_k = (const float*)d_in[5];
  const float* b_k = (const float*)d_in[6];
  const float* W_v = (const float*)d_in[7];
  const float* b_v = (const float*)d_in[8];
  const float* W_o = (const float*)d_in[9];
  const float* b_o = (const float*)d_in[10];

  const size_t SD  = (size_t)BATCH * SEQ * DM;          // 8,388,608 elems
  const size_t SDB = SD * 2;                            // bytes per bf16 buffer
  const size_t D2  = (size_t)DM * DM;                   // 1,048,576 elems
  if (ws_size < 5 * SDB + D2 * 2) return;               // ~86 MB (same as v2)

  char* base = (char*)d_ws;
  unsigned short* B0 = (unsigned short*)(base);             // XQ -> AO
  unsigned short* B1 = (unsigned short*)(base + 1 * SDB);   // XK -> Vt
  unsigned short* B2 = (unsigned short*)(base + 2 * SDB);   // XV
  unsigned short* B3 = (unsigned short*)(base + 3 * SDB);   // Qp
  unsigned short* B4 = (unsigned short*)(base + 4 * SDB);   // Kp
  unsigned short* Wb = (unsigned short*)(base + 5 * SDB);   // Wo bf16 (2MB)

  // bf16 Wq/Wk/Wv parked in d_out's front 6MB (fully overwritten by O-GEMM later)
  unsigned short* dW0 = (unsigned short*)d_out;             // Wq
  unsigned short* dW1 = dW0 + D2;                           // Wk
  unsigned short* dW2 = dW0 + 2 * D2;                       // Wv

  const int nSD4 = (int)(SD / 4), nD24 = (int)(D2 / 4);
  const dim3 blk(256);

  cvt3_k<<<dim3(nSD4 / 256, 3), blk, 0, stream>>>(q, k, v, B0, B1, B2, nSD4);
  cvt4_k<<<dim3(nD24 / 256, 4), blk, 0, stream>>>(W_q, W_k, W_v, W_o, dW0, dW1, dW2, Wb, nD24);
  // Q and K projections (one dispatch)
  gemm_qk<<<dim3(DM / 128, (BATCH * SEQ) / 128, 2), blk, 0, stream>>>(
      B0, B1, dW0, dW1, b_q, b_k, B3, B4, BATCH * SEQ, DM, DM);
  // V projection, transposed output: Vt[d, b*S+s] = (W_v XV^T)[d, i] + b_v[d]
  gemm_bt<true, false><<<dim3((BATCH * SEQ) / 128, DM / 128), blk, 0, stream>>>(
      dW2, B2, b_v, B1, DM, BATCH * SEQ, DM);
  // fused attention
  attn_k<<<dim3(16 * NH * BATCH), blk, 0, stream>>>(B3, B4, B1, B0);
  // output projection -> fp32
  gemm_bt<false, true><<<dim3(DM / 128, (BATCH * SEQ) / 128), blk, 0, stream>>>(
      B0, Wb, b_o, d_out, BATCH * SEQ, DM, DM);
}

// Round 4
// 235.785 us; speedup vs baseline: 1.6030x; 1.0367x over previous
//
#include <hip/hip_runtime.h>

// MHA: out = softmax((XQ Wq^T + bq)(XK Wk^T + bk)^T / sqrt(64)) (XV Wv^T + bv) Wo^T + bo
// B=4, S=2048, D=1024, H=16, Dh=64. All matmuls bf16 MFMA 16x16x32, fp32 accum.
//
// v4: attn LDS 48->40KB (P packed/consumed in two kv-32 halves) so 4 blocks/CU
// and the 1024-block grid packs in ONE residency round (was 3/CU + tail round).
// launch_bounds(256,4), pointer-increment staging, f32x4 reduce trees, setprio.

#define BATCH 4
#define SEQ   2048
#define NH    16
#define DH    64
#define DM    1024
#define LOG2E 1.4426950408889634f
#define CSC   (0.125f * LOG2E)   // softmax scale folded into exp2 domain

typedef __attribute__((ext_vector_type(8))) short s16x8;
typedef __attribute__((ext_vector_type(4))) float f32x4;
typedef const __attribute__((address_space(1))) unsigned int* gas1;
typedef __attribute__((address_space(3))) unsigned int* las3;

__device__ __forceinline__ unsigned short f2bf(float f) {
  unsigned int u = __float_as_uint(f);
  u += 0x7FFFu + ((u >> 16) & 1u);   // RTNE
  return (unsigned short)(u >> 16);
}

__device__ __forceinline__ unsigned int cvt_pk_bf16(float lo, float hi) {
  unsigned int r;
  asm("v_cvt_pk_bf16_f32 %0, %1, %2" : "=v"(r) : "v"(lo), "v"(hi));
  return r;
}

__device__ __forceinline__ f32x4 vmax4(f32x4 a, f32x4 b) {
  f32x4 r;
  r[0] = fmaxf(a[0], b[0]); r[1] = fmaxf(a[1], b[1]);
  r[2] = fmaxf(a[2], b[2]); r[3] = fmaxf(a[3], b[3]);
  return r;
}

// ---------------- fp32 -> bf16, 3 tensors in one launch ----------------
__global__ __launch_bounds__(256) void cvt3_k(const float* __restrict__ s0,
                                              const float* __restrict__ s1,
                                              const float* __restrict__ s2,
                                              unsigned short* __restrict__ d0,
                                              unsigned short* __restrict__ d1,
                                              unsigned short* __restrict__ d2, int n4) {
  const float* s = blockIdx.y == 0 ? s0 : blockIdx.y == 1 ? s1 : s2;
  unsigned short* d = blockIdx.y == 0 ? d0 : blockIdx.y == 1 ? d1 : d2;
  int i = blockIdx.x * 256 + threadIdx.x;
  if (i < n4) {
    float4 v = ((const float4*)s)[i];
    ushort4 o;
    o.x = f2bf(v.x); o.y = f2bf(v.y); o.z = f2bf(v.z); o.w = f2bf(v.w);
    ((ushort4*)d)[i] = o;
  }
}

// ---------------- fp32 -> bf16, 4 weight matrices in one launch ----------------
__global__ __launch_bounds__(256) void cvt4_k(const float* __restrict__ s0,
                                              const float* __restrict__ s1,
                                              const float* __restrict__ s2,
                                              const float* __restrict__ s3,
                                              unsigned short* __restrict__ d0,
                                              unsigned short* __restrict__ d1,
                                              unsigned short* __restrict__ d2,
                                              unsigned short* __restrict__ d3, int n4) {
  const float* s = blockIdx.y == 0 ? s0 : blockIdx.y == 1 ? s1 : blockIdx.y == 2 ? s2 : s3;
  unsigned short* d = blockIdx.y == 0 ? d0 : blockIdx.y == 1 ? d1 : blockIdx.y == 2 ? d2 : d3;
  int i = blockIdx.x * 256 + threadIdx.x;
  if (i < n4) {
    float4 v = ((const float4*)s)[i];
    ushort4 o;
    o.x = f2bf(v.x); o.y = f2bf(v.y); o.z = f2bf(v.z); o.w = f2bf(v.w);
    ((ushort4*)d)[i] = o;
  }
}

// ---------------- GEMM core: C[M,N] = A[M,K] * B[N,K]^T + bias ----------------
template<bool BIAS_ROW, bool OUT_F32>
__device__ __forceinline__ void gemm_core(const unsigned short* __restrict__ A,
                                          const unsigned short* __restrict__ Bm,
                                          const float* __restrict__ bias,
                                          void* __restrict__ Cout,
                                          int M, int N, int K, int tM, int tN,
                                          unsigned short* As, unsigned short* Bs) {
  const int tid = threadIdx.x;
  const int wave = tid >> 6, lane = tid & 63;
  const int lr = lane & 15, lh = lane >> 4;
  const int wm = (wave >> 1) * 64, wn = (wave & 1) * 64;
  f32x4 acc[4][4] = {};

  for (int k0 = 0; k0 < K; k0 += 64) {
    __syncthreads();
#pragma unroll
    for (int i = 0; i < 4; ++i) {
      const int slot = wave * 256 + i * 64 + lane;
      const int row = slot >> 3;
      const int cg = (slot & 7) ^ (row & 7);   // inverse-swizzled source chunk
      const unsigned short* ga = A  + (size_t)(tM * 128 + row) * K + k0 + cg * 8;
      const unsigned short* gb = Bm + (size_t)(tN * 128 + row) * K + k0 + cg * 8;
      __builtin_amdgcn_global_load_lds((gas1)ga, (las3)(As + (wave * 256 + i * 64) * 8), 16, 0, 0);
      __builtin_amdgcn_global_load_lds((gas1)gb, (las3)(Bs + (wave * 256 + i * 64) * 8), 16, 0, 0);
    }
    __syncthreads();

    s16x8 af[4][2], bfr[4][2];
#pragma unroll
    for (int mt = 0; mt < 4; ++mt) {
#pragma unroll
      for (int kt = 0; kt < 2; ++kt) {
        const int ra = wm + mt * 16 + lr;
        af[mt][kt] = *(const s16x8*)(As + ra * 64 + (((kt * 4 + lh) ^ (ra & 7)) * 8));
        const int rb = wn + mt * 16 + lr;
        bfr[mt][kt] = *(const s16x8*)(Bs + rb * 64 + (((kt * 4 + lh) ^ (rb & 7)) * 8));
      }
    }
#pragma unroll
    for (int mt = 0; mt < 4; ++mt) {
#pragma unroll
      for (int nt = 0; nt < 4; ++nt) {
        acc[mt][nt] = __builtin_amdgcn_mfma_f32_16x16x32_bf16(af[mt][0], bfr[nt][0], acc[mt][nt], 0, 0, 0);
        acc[mt][nt] = __builtin_amdgcn_mfma_f32_16x16x32_bf16(af[mt][1], bfr[nt][1], acc[mt][nt], 0, 0, 0);
      }
    }
  }

#pragma unroll
  for (int mt = 0; mt < 4; ++mt) {
#pragma unroll
    for (int nt = 0; nt < 4; ++nt) {
      const int row0 = tM * 128 + wm + mt * 16 + lh * 4;
      const int col  = tN * 128 + wn + nt * 16 + lr;
      const float bc = BIAS_ROW ? 0.f : bias[col];
#pragma unroll
      for (int r = 0; r < 4; ++r) {
        const float v = acc[mt][nt][r] + (BIAS_ROW ? bias[row0 + r] : bc);
        if (OUT_F32) ((float*)Cout)[(size_t)(row0 + r) * N + col] = v;
        else ((unsigned short*)Cout)[(size_t)(row0 + r) * N + col] = f2bf(v);
      }
    }
  }
}

template<bool BIAS_ROW, bool OUT_F32>
__global__ __launch_bounds__(256) void gemm_bt(const unsigned short* __restrict__ A,
                                               const unsigned short* __restrict__ Bm,
                                               const float* __restrict__ bias,
                                               void* __restrict__ Cout, int M, int N, int K) {
  __shared__ unsigned short As[128 * 64];
  __shared__ unsigned short Bs[128 * 64];
  gemm_core<BIAS_ROW, OUT_F32>(A, Bm, bias, Cout, M, N, K, blockIdx.y, blockIdx.x, As, Bs);
}

// Q and K projections merged: blockIdx.z selects the operand set.
__global__ __launch_bounds__(256) void gemm_qk(const unsigned short* __restrict__ A0,
                                               const unsigned short* __restrict__ A1,
                                               const unsigned short* __restrict__ W0,
                                               const unsigned short* __restrict__ W1,
                                               const float* __restrict__ c0,
                                               const float* __restrict__ c1,
                                               void* __restrict__ C0, void* __restrict__ C1,
                                               int M, int N, int K) {
  __shared__ unsigned short As[128 * 64];
  __shared__ unsigned short Bs[128 * 64];
  if (blockIdx.z == 0)
    gemm_core<false, false>(A0, W0, c0, C0, M, N, K, blockIdx.y, blockIdx.x, As, Bs);
  else
    gemm_core<false, false>(A1, W1, c1, C1, M, N, K, blockIdx.y, blockIdx.x, As, Bs);
}

// ---------------- fused flash attention v4 ----------------
// 1D grid 1024 (XCD-swizzled), 256 thr = 4 waves, QBLK=32/wave, KVBLK=64.
// LDS 40KB (K dbuf 16 + V dbuf 16 + P 8) -> 4 blocks/CU, grid packs in 1 round.
__global__ __launch_bounds__(256, 4) void attn_k(const unsigned short* __restrict__ Q,
                                                 const unsigned short* __restrict__ Kp,
                                                 const unsigned short* __restrict__ Vt,
                                                 unsigned short* __restrict__ AO) {
  __shared__ unsigned short Ks[2][64 * 64];     // [kv][d]  2 x 8KB
  __shared__ unsigned short Vs[2][64 * 64];     // [d][kv]  2 x 8KB
  __shared__ unsigned short Ps[4 * 32 * 32];    // per-wave [q 32][kv 32] (one half), 8KB
  const int tid = threadIdx.x;
  const int w = tid >> 6, lane = tid & 63;
  const int lr = lane & 15, lh = lane >> 4;
  const int sw = lr & 7;          // 3-bit key for 64-wide K/V rows
  const int sp = lr & 3;          // 2-bit key for 32-wide P rows

  // XCD-aware swizzle: 8 consecutive (b,h) pairs per XCD (per-XCD KV ~4MB = L2)
  const int id = blockIdx.x;                    // 0..1023
  const int g  = (id & 7) * 128 + (id >> 3);    // bijective (1024 % 8 == 0)
  const int qt = g & 15;
  const int hb = g >> 4;
  const int h = hb & 15, b = hb >> 4;

  s16x8 qf[2][2];
#pragma unroll
  for (int qb = 0; qb < 2; ++qb)
#pragma unroll
    for (int kt = 0; kt < 2; ++kt)
      qf[qb][kt] = *(const s16x8*)(Q + (size_t)(b * SEQ + qt * 128 + w * 32 + qb * 16 + lr) * DM
                                     + h * DH + kt * 32 + lh * 8);
  asm volatile("s_waitcnt vmcnt(0)" ::: "memory");   // qf resident; vmcnt accounting clean
  __builtin_amdgcn_sched_barrier(0);

  f32x4 o[2][4] = {};
  float m_run[2] = {-1e30f, -1e30f};
  float l_run[2] = {0.f, 0.f};
  unsigned short* Pw = Ps + w * 1024;

  const unsigned short* Kbase = Kp + (size_t)b * SEQ * DM + h * DH;
  const unsigned short* Vbase = Vt + (size_t)h * DH * (BATCH * SEQ) + (size_t)b * SEQ;

  // per-lane staging pointers (advance by constant strides per tile)
  const int slot0 = w * 64 + lane, slot1 = 256 + w * 64 + lane;
  const int r0 = slot0 >> 3, c0 = (slot0 & 7) ^ (r0 & 7);
  const int r1 = slot1 >> 3, c1 = (slot1 & 7) ^ (r1 & 7);
  const unsigned short* gk0 = Kbase + (size_t)r0 * DM + c0 * 8;
  const unsigned short* gk1 = Kbase + (size_t)r1 * DM + c1 * 8;
  const unsigned short* gv0 = Vbase + (size_t)r0 * (BATCH * SEQ) + c0 * 8;
  const unsigned short* gv1 = Vbase + (size_t)r1 * (BATCH * SEQ) + c1 * 8;
  const int dst0 = (w * 64) * 8, dst1 = (256 + w * 64) * 8;

  auto stage = [&](int buf) {
    __builtin_amdgcn_global_load_lds((gas1)gk0, (las3)(&Ks[buf][dst0]), 16, 0, 0);
    __builtin_amdgcn_global_load_lds((gas1)gk1, (las3)(&Ks[buf][dst1]), 16, 0, 0);
    __builtin_amdgcn_global_load_lds((gas1)gv0, (las3)(&Vs[buf][dst0]), 16, 0, 0);
    __builtin_amdgcn_global_load_lds((gas1)gv1, (las3)(&Vs[buf][dst1]), 16, 0, 0);
    gk0 += 64 * DM; gk1 += 64 * DM; gv0 += 64; gv1 += 64;
  };

  stage(0);
  for (int t = 0; t < 32; ++t) {
    const int cur = t & 1;
    if (t < 31) {
      stage(cur ^ 1);                                 // prefetch next tile
      asm volatile("s_waitcnt vmcnt(4)" ::: "memory");// cur's 4 loads done; next 4 in flight
    } else {
      asm volatile("s_waitcnt vmcnt(0)" ::: "memory");
    }
    __builtin_amdgcn_s_barrier();
    __builtin_amdgcn_sched_barrier(0);
    const unsigned short* Kc = Ks[cur];
    const unsigned short* Vc = Vs[cur];

    // QK^T (swapped operands): rows = kv, cols = q
    f32x4 s[2][4] = {};
    __builtin_amdgcn_s_setprio(1);
#pragma unroll
    for (int nt = 0; nt < 4; ++nt) {
#pragma unroll
      for (int kt = 0; kt < 2; ++kt) {
        const s16x8 kf = *(const s16x8*)(Kc + (nt * 16 + lr) * 64 + (((kt * 4 + lh) ^ sw) * 8));
        s[0][nt] = __builtin_amdgcn_mfma_f32_16x16x32_bf16(kf, qf[0][kt], s[0][nt], 0, 0, 0);
        s[1][nt] = __builtin_amdgcn_mfma_f32_16x16x32_bf16(kf, qf[1][kt], s[1][nt], 0, 0, 0);
      }
    }
    __builtin_amdgcn_s_setprio(0);

    // online softmax, lane-local (q = lr), defer-max rescale
    f32x4 p[2][4];
#pragma unroll
    for (int qb = 0; qb < 2; ++qb) {
      const f32x4 m03 = vmax4(vmax4(s[qb][0], s[qb][1]), vmax4(s[qb][2], s[qb][3]));
      float mx = fmaxf(fmaxf(m03[0], m03[1]), fmaxf(m03[2], m03[3]));
      mx = fmaxf(mx, __shfl_xor(mx, 16));
      mx = fmaxf(mx, __shfl_xor(mx, 32));
      if (!__all(mx - m_run[qb] <= 64.0f)) {   // 64 raw = 8 in exp-arg domain
        const float al = __builtin_amdgcn_exp2f((m_run[qb] - mx) * CSC);
        m_run[qb] = mx;
        l_run[qb] *= al;
#pragma unroll
        for (int dt = 0; dt < 4; ++dt) o[qb][dt] *= al;
      }
      const float base = m_run[qb] * CSC;
#pragma unroll
      for (int nt = 0; nt < 4; ++nt)
#pragma unroll
        for (int r = 0; r < 4; ++r)
          p[qb][nt][r] = __builtin_amdgcn_exp2f(s[qb][nt][r] * CSC - base);
      const f32x4 st = (p[qb][0] + p[qb][1]) + (p[qb][2] + p[qb][3]);
      float rs = (st[0] + st[1]) + (st[2] + st[3]);
      rs += __shfl_xor(rs, 16);
      rs += __shfl_xor(rs, 32);
      l_run[qb] += rs;
    }

    // PV in two kv-32 halves through the 8KB per-wave P buffer
#pragma unroll
    for (int hf = 0; hf < 2; ++hf) {
#pragma unroll
      for (int qb = 0; qb < 2; ++qb) {
        const int row = qb * 16 + lr;
#pragma unroll
        for (int ntl = 0; ntl < 2; ++ntl) {
          const int nt = hf * 2 + ntl;
          uint2 wd;
          wd.x = cvt_pk_bf16(p[qb][nt][0], p[qb][nt][1]);
          wd.y = cvt_pk_bf16(p[qb][nt][2], p[qb][nt][3]);
          const int cc = (ntl * 4 + lh) ^ (sp << 1);
          *(uint2*)(Pw + row * 32 + cc * 4) = wd;
        }
      }
      __builtin_amdgcn_s_setprio(1);
      const s16x8 pf0 = *(const s16x8*)(Pw + lr * 32        + ((lh ^ sp) * 8));
      const s16x8 pf1 = *(const s16x8*)(Pw + (16 + lr) * 32 + ((lh ^ sp) * 8));
#pragma unroll
      for (int dt = 0; dt < 4; ++dt) {
        const s16x8 vf = *(const s16x8*)(Vc + (dt * 16 + lr) * 64 + (((hf * 4 + lh) ^ sw) * 8));
        o[0][dt] = __builtin_amdgcn_mfma_f32_16x16x32_bf16(vf, pf0, o[0][dt], 0, 0, 0);
        o[1][dt] = __builtin_amdgcn_mfma_f32_16x16x32_bf16(vf, pf1, o[1][dt], 0, 0, 0);
      }
      __builtin_amdgcn_s_setprio(0);
    }
    __builtin_amdgcn_sched_barrier(0);
    __builtin_amdgcn_s_barrier();   // all waves done reading buf[cur] before it's restaged
  }

  // epilogue: normalize, pack pairs, store (O[q=lr][d])
#pragma unroll
  for (int qb = 0; qb < 2; ++qb) {
    const float rl = __builtin_amdgcn_rcpf(l_run[qb]);
    unsigned short* orow = AO + (size_t)(b * SEQ + qt * 128 + w * 32 + qb * 16 + lr) * DM + h * DH;
#pragma unroll
    for (int dt = 0; dt < 4; ++dt) {
      *(unsigned int*)(orow + dt * 16 + lh * 4)     = cvt_pk_bf16(o[qb][dt][0] * rl, o[qb][dt][1] * rl);
      *(unsigned int*)(orow + dt * 16 + lh * 4 + 2) = cvt_pk_bf16(o[qb][dt][2] * rl, o[qb][dt][3] * rl);
    }
  }
}

extern "C" void kernel_launch(void* const* d_in, const int* in_sizes, int n_in,
                              void* d_out, int out_size, void* d_ws, size_t ws_size,
                              hipStream_t stream) {
  const float* q   = (const float*)d_in[0];
  const float* k   = (const float*)d_in[1];
  const float* v   = (const float*)d_in[2];
  const float* W_q = (const float*)d_in[3];
  const float* b_q = (const float*)d_in[4];
  const float* W_k = (const float*)d_in[5];
  const float* b_k = (const float*)d_in[6];
  const float* W_v = (const float*)d_in[7];
  const float* b_v = (const float*)d_in[8];
  const float* W_o = (const float*)d_in[9];
  const float* b_o = (const float*)d_in[10];

  const size_t SD  = (size_t)BATCH * SEQ * DM;          // 8,388,608 elems
  const size_t SDB = SD * 2;                            // bytes per bf16 buffer
  const size_t D2  = (size_t)DM * DM;                   // 1,048,576 elems
  if (ws_size < 5 * SDB + D2 * 2) return;               // ~86 MB

  char* base = (char*)d_ws;
  unsigned short* B0 = (unsigned short*)(base);             // XQ -> AO
  unsigned short* B1 = (unsigned short*)(base + 1 * SDB);   // XK -> Vt
  unsigned short* B2 = (unsigned short*)(base + 2 * SDB);   // XV
  unsigned short* B3 = (unsigned short*)(base + 3 * SDB);   // Qp
  unsigned short* B4 = (unsigned short*)(base + 4 * SDB);   // Kp
  unsigned short* Wb = (unsigned short*)(base + 5 * SDB);   // Wo bf16 (2MB)

  // bf16 Wq/Wk/Wv parked in d_out's front 6MB (fully overwritten by O-GEMM later)
  unsigned short* dW0 = (unsigned short*)d_out;             // Wq
  unsigned short* dW1 = dW0 + D2;                           // Wk
  unsigned short* dW2 = dW0 + 2 * D2;                       // Wv

  const int nSD4 = (int)(SD / 4), nD24 = (int)(D2 / 4);
  const dim3 blk(256);

  cvt3_k<<<dim3(nSD4 / 256, 3), blk, 0, stream>>>(q, k, v, B0, B1, B2, nSD4);
  cvt4_k<<<dim3(nD24 / 256, 4), blk, 0, stream>>>(W_q, W_k, W_v, W_o, dW0, dW1, dW2, Wb, nD24);
  // Q and K projections (one dispatch)
  gemm_qk<<<dim3(DM / 128, (BATCH * SEQ) / 128, 2), blk, 0, stream>>>(
      B0, B1, dW0, dW1, b_q, b_k, B3, B4, BATCH * SEQ, DM, DM);
  // V projection, transposed output: Vt[d, b*S+s] = (W_v XV^T)[d, i] + b_v[d]
  gemm_bt<true, false><<<dim3((BATCH * SEQ) / 128, DM / 128), blk, 0, stream>>>(
      dW2, B2, b_v, B1, DM, BATCH * SEQ, DM);
  // fused attention
  attn_k<<<dim3(16 * NH * BATCH), blk, 0, stream>>>(B3, B4, B1, B0);
  // output projection -> fp32
  gemm_bt<false, true><<<dim3(DM / 128, (BATCH * SEQ) / 128), blk, 0, stream>>>(
      B0, Wb, b_o, d_out, BATCH * SEQ, DM, DM);
}

// Round 5
// 229.981 us; speedup vs baseline: 1.6435x; 1.0252x over previous
//
#include <hip/hip_runtime.h>

// MHA: out = softmax((XQ Wq^T + bq)(XK Wk^T + bk)^T / sqrt(64)) (XV Wv^T + bv) Wo^T + bo
// B=4, S=2048, D=1024, H=16, Dh=64. All matmuls bf16 MFMA 16x16x32, fp32 accum.
//
// v5: conflict-free P staging. Per-wave per-qb P buffer [16q][128B] with
// additive 8B-slot rotation (slot+lr)&15 -> every 16-lane group covers all 32
// banks exactly once on both ds_write_b64 and ds_read_b64. LDS stays 40KB
// (4 blocks/CU). Everything else identical to v4.

#define BATCH 4
#define SEQ   2048
#define NH    16
#define DH    64
#define DM    1024
#define LOG2E 1.4426950408889634f
#define CSC   (0.125f * LOG2E)   // softmax scale folded into exp2 domain

typedef __attribute__((ext_vector_type(8))) short s16x8;
typedef __attribute__((ext_vector_type(4))) float f32x4;
typedef __attribute__((ext_vector_type(4))) unsigned int u32x4;
typedef const __attribute__((address_space(1))) unsigned int* gas1;
typedef __attribute__((address_space(3))) unsigned int* las3;

__device__ __forceinline__ unsigned short f2bf(float f) {
  unsigned int u = __float_as_uint(f);
  u += 0x7FFFu + ((u >> 16) & 1u);   // RTNE
  return (unsigned short)(u >> 16);
}

__device__ __forceinline__ unsigned int cvt_pk_bf16(float lo, float hi) {
  unsigned int r;
  asm("v_cvt_pk_bf16_f32 %0, %1, %2" : "=v"(r) : "v"(lo), "v"(hi));
  return r;
}

__device__ __forceinline__ f32x4 vmax4(f32x4 a, f32x4 b) {
  f32x4 r;
  r[0] = fmaxf(a[0], b[0]); r[1] = fmaxf(a[1], b[1]);
  r[2] = fmaxf(a[2], b[2]); r[3] = fmaxf(a[3], b[3]);
  return r;
}

// ---------------- fp32 -> bf16, 3 tensors in one launch ----------------
__global__ __launch_bounds__(256) void cvt3_k(const float* __restrict__ s0,
                                              const float* __restrict__ s1,
                                              const float* __restrict__ s2,
                                              unsigned short* __restrict__ d0,
                                              unsigned short* __restrict__ d1,
                                              unsigned short* __restrict__ d2, int n4) {
  const float* s = blockIdx.y == 0 ? s0 : blockIdx.y == 1 ? s1 : s2;
  unsigned short* d = blockIdx.y == 0 ? d0 : blockIdx.y == 1 ? d1 : d2;
  int i = blockIdx.x * 256 + threadIdx.x;
  if (i < n4) {
    float4 v = ((const float4*)s)[i];
    ushort4 o;
    o.x = f2bf(v.x); o.y = f2bf(v.y); o.z = f2bf(v.z); o.w = f2bf(v.w);
    ((ushort4*)d)[i] = o;
  }
}

// ---------------- fp32 -> bf16, 4 weight matrices in one launch ----------------
__global__ __launch_bounds__(256) void cvt4_k(const float* __restrict__ s0,
                                              const float* __restrict__ s1,
                                              const float* __restrict__ s2,
                                              const float* __restrict__ s3,
                                              unsigned short* __restrict__ d0,
                                              unsigned short* __restrict__ d1,
                                              unsigned short* __restrict__ d2,
                                              unsigned short* __restrict__ d3, int n4) {
  const float* s = blockIdx.y == 0 ? s0 : blockIdx.y == 1 ? s1 : blockIdx.y == 2 ? s2 : s3;
  unsigned short* d = blockIdx.y == 0 ? d0 : blockIdx.y == 1 ? d1 : blockIdx.y == 2 ? d2 : d3;
  int i = blockIdx.x * 256 + threadIdx.x;
  if (i < n4) {
    float4 v = ((const float4*)s)[i];
    ushort4 o;
    o.x = f2bf(v.x); o.y = f2bf(v.y); o.z = f2bf(v.z); o.w = f2bf(v.w);
    ((ushort4*)d)[i] = o;
  }
}

// ---------------- GEMM core: C[M,N] = A[M,K] * B[N,K]^T + bias ----------------
template<bool BIAS_ROW, bool OUT_F32>
__device__ __forceinline__ void gemm_core(const unsigned short* __restrict__ A,
                                          const unsigned short* __restrict__ Bm,
                                          const float* __restrict__ bias,
                                          void* __restrict__ Cout,
                                          int M, int N, int K, int tM, int tN,
                                          unsigned short* As, unsigned short* Bs) {
  const int tid = threadIdx.x;
  const int wave = tid >> 6, lane = tid & 63;
  const int lr = lane & 15, lh = lane >> 4;
  const int wm = (wave >> 1) * 64, wn = (wave & 1) * 64;
  f32x4 acc[4][4] = {};

  for (int k0 = 0; k0 < K; k0 += 64) {
    __syncthreads();
#pragma unroll
    for (int i = 0; i < 4; ++i) {
      const int slot = wave * 256 + i * 64 + lane;
      const int row = slot >> 3;
      const int cg = (slot & 7) ^ (row & 7);   // inverse-swizzled source chunk
      const unsigned short* ga = A  + (size_t)(tM * 128 + row) * K + k0 + cg * 8;
      const unsigned short* gb = Bm + (size_t)(tN * 128 + row) * K + k0 + cg * 8;
      __builtin_amdgcn_global_load_lds((gas1)ga, (las3)(As + (wave * 256 + i * 64) * 8), 16, 0, 0);
      __builtin_amdgcn_global_load_lds((gas1)gb, (las3)(Bs + (wave * 256 + i * 64) * 8), 16, 0, 0);
    }
    __syncthreads();

    s16x8 af[4][2], bfr[4][2];
#pragma unroll
    for (int mt = 0; mt < 4; ++mt) {
#pragma unroll
      for (int kt = 0; kt < 2; ++kt) {
        const int ra = wm + mt * 16 + lr;
        af[mt][kt] = *(const s16x8*)(As + ra * 64 + (((kt * 4 + lh) ^ (ra & 7)) * 8));
        const int rb = wn + mt * 16 + lr;
        bfr[mt][kt] = *(const s16x8*)(Bs + rb * 64 + (((kt * 4 + lh) ^ (rb & 7)) * 8));
      }
    }
#pragma unroll
    for (int mt = 0; mt < 4; ++mt) {
#pragma unroll
      for (int nt = 0; nt < 4; ++nt) {
        acc[mt][nt] = __builtin_amdgcn_mfma_f32_16x16x32_bf16(af[mt][0], bfr[nt][0], acc[mt][nt], 0, 0, 0);
        acc[mt][nt] = __builtin_amdgcn_mfma_f32_16x16x32_bf16(af[mt][1], bfr[nt][1], acc[mt][nt], 0, 0, 0);
      }
    }
  }

#pragma unroll
  for (int mt = 0; mt < 4; ++mt) {
#pragma unroll
    for (int nt = 0; nt < 4; ++nt) {
      const int row0 = tM * 128 + wm + mt * 16 + lh * 4;
      const int col  = tN * 128 + wn + nt * 16 + lr;
      const float bc = BIAS_ROW ? 0.f : bias[col];
#pragma unroll
      for (int r = 0; r < 4; ++r) {
        const float v = acc[mt][nt][r] + (BIAS_ROW ? bias[row0 + r] : bc);
        if (OUT_F32) ((float*)Cout)[(size_t)(row0 + r) * N + col] = v;
        else ((unsigned short*)Cout)[(size_t)(row0 + r) * N + col] = f2bf(v);
      }
    }
  }
}

template<bool BIAS_ROW, bool OUT_F32>
__global__ __launch_bounds__(256) void gemm_bt(const unsigned short* __restrict__ A,
                                               const unsigned short* __restrict__ Bm,
                                               const float* __restrict__ bias,
                                               void* __restrict__ Cout, int M, int N, int K) {
  __shared__ unsigned short As[128 * 64];
  __shared__ unsigned short Bs[128 * 64];
  gemm_core<BIAS_ROW, OUT_F32>(A, Bm, bias, Cout, M, N, K, blockIdx.y, blockIdx.x, As, Bs);
}

// Q and K projections merged: blockIdx.z selects the operand set.
__global__ __launch_bounds__(256) void gemm_qk(const unsigned short* __restrict__ A0,
                                               const unsigned short* __restrict__ A1,
                                               const unsigned short* __restrict__ W0,
                                               const unsigned short* __restrict__ W1,
                                               const float* __restrict__ c0,
                                               const float* __restrict__ c1,
                                               void* __restrict__ C0, void* __restrict__ C1,
                                               int M, int N, int K) {
  __shared__ unsigned short As[128 * 64];
  __shared__ unsigned short Bs[128 * 64];
  if (blockIdx.z == 0)
    gemm_core<false, false>(A0, W0, c0, C0, M, N, K, blockIdx.y, blockIdx.x, As, Bs);
  else
    gemm_core<false, false>(A1, W1, c1, C1, M, N, K, blockIdx.y, blockIdx.x, As, Bs);
}

// ---------------- fused flash attention v5 ----------------
// 1D grid 1024 (XCD-swizzled), 256 thr = 4 waves, QBLK=32/wave, KVBLK=64.
// K/V double-buffered (counted vmcnt); P per-wave per-qb [16q][128B] with
// additive 8B-slot rotation -> conflict-free ds_write_b64 / ds_read_b64.
__global__ __launch_bounds__(256, 4) void attn_k(const unsigned short* __restrict__ Q,
                                                 const unsigned short* __restrict__ Kp,
                                                 const unsigned short* __restrict__ Vt,
                                                 unsigned short* __restrict__ AO) {
  __shared__ unsigned short Ks[2][64 * 64];     // [kv][d]  2 x 8KB
  __shared__ unsigned short Vs[2][64 * 64];     // [d][kv]  2 x 8KB
  __shared__ unsigned short Ps[4][16 * 64];     // per-wave [q 16][kv 64] (one qb), 8KB
  const int tid = threadIdx.x;
  const int w = tid >> 6, lane = tid & 63;
  const int lr = lane & 15, lh = lane >> 4;
  const int sw = lr & 7;          // 3-bit key for 64-wide K/V rows

  // XCD-aware swizzle: 8 consecutive (b,h) pairs per XCD (per-XCD KV ~4MB = L2)
  const int id = blockIdx.x;                    // 0..1023
  const int g  = (id & 7) * 128 + (id >> 3);    // bijective (1024 % 8 == 0)
  const int qt = g & 15;
  const int hb = g >> 4;
  const int h = hb & 15, b = hb >> 4;

  s16x8 qf[2][2];
#pragma unroll
  for (int qb = 0; qb < 2; ++qb)
#pragma unroll
    for (int kt = 0; kt < 2; ++kt)
      qf[qb][kt] = *(const s16x8*)(Q + (size_t)(b * SEQ + qt * 128 + w * 32 + qb * 16 + lr) * DM
                                     + h * DH + kt * 32 + lh * 8);
  asm volatile("s_waitcnt vmcnt(0)" ::: "memory");   // qf resident; vmcnt accounting clean
  __builtin_amdgcn_sched_barrier(0);

  f32x4 o[2][4] = {};
  float m_run[2] = {-1e30f, -1e30f};
  float l_run[2] = {0.f, 0.f};
  unsigned short* Pw = Ps[w];

  const unsigned short* Kbase = Kp + (size_t)b * SEQ * DM + h * DH;
  const unsigned short* Vbase = Vt + (size_t)h * DH * (BATCH * SEQ) + (size_t)b * SEQ;

  // per-lane staging pointers (advance by constant strides per tile)
  const int slot0 = w * 64 + lane, slot1 = 256 + w * 64 + lane;
  const int r0 = slot0 >> 3, c0 = (slot0 & 7) ^ (r0 & 7);
  const int r1 = slot1 >> 3, c1 = (slot1 & 7) ^ (r1 & 7);
  const unsigned short* gk0 = Kbase + (size_t)r0 * DM + c0 * 8;
  const unsigned short* gk1 = Kbase + (size_t)r1 * DM + c1 * 8;
  const unsigned short* gv0 = Vbase + (size_t)r0 * (BATCH * SEQ) + c0 * 8;
  const unsigned short* gv1 = Vbase + (size_t)r1 * (BATCH * SEQ) + c1 * 8;
  const int dst0 = (w * 64) * 8, dst1 = (256 + w * 64) * 8;

  auto stage = [&](int buf) {
    __builtin_amdgcn_global_load_lds((gas1)gk0, (las3)(&Ks[buf][dst0]), 16, 0, 0);
    __builtin_amdgcn_global_load_lds((gas1)gk1, (las3)(&Ks[buf][dst1]), 16, 0, 0);
    __builtin_amdgcn_global_load_lds((gas1)gv0, (las3)(&Vs[buf][dst0]), 16, 0, 0);
    __builtin_amdgcn_global_load_lds((gas1)gv1, (las3)(&Vs[buf][dst1]), 16, 0, 0);
    gk0 += 64 * DM; gk1 += 64 * DM; gv0 += 64; gv1 += 64;
  };

  stage(0);
  for (int t = 0; t < 32; ++t) {
    const int cur = t & 1;
    if (t < 31) {
      stage(cur ^ 1);                                 // prefetch next tile
      asm volatile("s_waitcnt vmcnt(4)" ::: "memory");// cur's 4 loads done; next 4 in flight
    } else {
      asm volatile("s_waitcnt vmcnt(0)" ::: "memory");
    }
    __builtin_amdgcn_s_barrier();
    __builtin_amdgcn_sched_barrier(0);
    const unsigned short* Kc = Ks[cur];
    const unsigned short* Vc = Vs[cur];

    // QK^T (swapped operands): rows = kv, cols = q
    f32x4 s[2][4] = {};
    __builtin_amdgcn_s_setprio(1);
#pragma unroll
    for (int nt = 0; nt < 4; ++nt) {
#pragma unroll
      for (int kt = 0; kt < 2; ++kt) {
        const s16x8 kf = *(const s16x8*)(Kc + (nt * 16 + lr) * 64 + (((kt * 4 + lh) ^ sw) * 8));
        s[0][nt] = __builtin_amdgcn_mfma_f32_16x16x32_bf16(kf, qf[0][kt], s[0][nt], 0, 0, 0);
        s[1][nt] = __builtin_amdgcn_mfma_f32_16x16x32_bf16(kf, qf[1][kt], s[1][nt], 0, 0, 0);
      }
    }
    __builtin_amdgcn_s_setprio(0);

    // online softmax, lane-local (q = lr), defer-max rescale; p overwrites s
#pragma unroll
    for (int qb = 0; qb < 2; ++qb) {
      const f32x4 m03 = vmax4(vmax4(s[qb][0], s[qb][1]), vmax4(s[qb][2], s[qb][3]));
      float mx = fmaxf(fmaxf(m03[0], m03[1]), fmaxf(m03[2], m03[3]));
      mx = fmaxf(mx, __shfl_xor(mx, 16));
      mx = fmaxf(mx, __shfl_xor(mx, 32));
      if (!__all(mx - m_run[qb] <= 64.0f)) {   // 64 raw = 8 in exp-arg domain
        const float al = __builtin_amdgcn_exp2f((m_run[qb] - mx) * CSC);
        m_run[qb] = mx;
        l_run[qb] *= al;
#pragma unroll
        for (int dt = 0; dt < 4; ++dt) o[qb][dt] *= al;
      }
      const float base = m_run[qb] * CSC;
#pragma unroll
      for (int nt = 0; nt < 4; ++nt)
#pragma unroll
        for (int r = 0; r < 4; ++r)
          s[qb][nt][r] = __builtin_amdgcn_exp2f(s[qb][nt][r] * CSC - base);
      const f32x4 st = (s[qb][0] + s[qb][1]) + (s[qb][2] + s[qb][3]);
      float rs = (st[0] + st[1]) + (st[2] + st[3]);
      rs += __shfl_xor(rs, 16);
      rs += __shfl_xor(rs, 32);
      l_run[qb] += rs;
    }

    // PV per qb through the rotated per-wave P buffer (conflict-free b64 ops)
#pragma unroll
    for (int qb = 0; qb < 2; ++qb) {
      // write P: lane holds kv {nt*16+lh*4 .. +3} for q=lr -> slot (nt*4+lh+lr)&15
#pragma unroll
      for (int nt = 0; nt < 4; ++nt) {
        uint2 wd;
        wd.x = cvt_pk_bf16(s[qb][nt][0], s[qb][nt][1]);
        wd.y = cvt_pk_bf16(s[qb][nt][2], s[qb][nt][3]);
        const int cp = (nt * 4 + lh + lr) & 15;
        *(uint2*)(Pw + lr * 64 + cp * 4) = wd;
      }
      // read pf (B-frag: kv = hf*32 + lh*8 + j, q=lr) as two rotated b64 reads
#pragma unroll
      for (int hf = 0; hf < 2; ++hf) {
        const int ca = (hf * 8 + lh * 2 + lr) & 15;
        const int cb = (hf * 8 + lh * 2 + 1 + lr) & 15;
        const uint2 lo = *(const uint2*)(Pw + lr * 64 + ca * 4);
        const uint2 hi = *(const uint2*)(Pw + lr * 64 + cb * 4);
        u32x4 pu;
        pu[0] = lo.x; pu[1] = lo.y; pu[2] = hi.x; pu[3] = hi.y;
        const s16x8 pf = __builtin_bit_cast(s16x8, pu);
        __builtin_amdgcn_s_setprio(1);
#pragma unroll
        for (int dt = 0; dt < 4; ++dt) {
          const s16x8 vf = *(const s16x8*)(Vc + (dt * 16 + lr) * 64 + (((hf * 4 + lh) ^ sw) * 8));
          o[qb][dt] = __builtin_amdgcn_mfma_f32_16x16x32_bf16(vf, pf, o[qb][dt], 0, 0, 0);
        }
        __builtin_amdgcn_s_setprio(0);
      }
    }
    __builtin_amdgcn_sched_barrier(0);
    __builtin_amdgcn_s_barrier();   // all waves done reading buf[cur] before it's restaged
  }

  // epilogue: normalize, pack pairs, store (O[q=lr][d])
#pragma unroll
  for (int qb = 0; qb < 2; ++qb) {
    const float rl = __builtin_amdgcn_rcpf(l_run[qb]);
    unsigned short* orow = AO + (size_t)(b * SEQ + qt * 128 + w * 32 + qb * 16 + lr) * DM + h * DH;
#pragma unroll
    for (int dt = 0; dt < 4; ++dt) {
      *(unsigned int*)(orow + dt * 16 + lh * 4)     = cvt_pk_bf16(o[qb][dt][0] * rl, o[qb][dt][1] * rl);
      *(unsigned int*)(orow + dt * 16 + lh * 4 + 2) = cvt_pk_bf16(o[qb][dt][2] * rl, o[qb][dt][3] * rl);
    }
  }
}

extern "C" void kernel_launch(void* const* d_in, const int* in_sizes, int n_in,
                              void* d_out, int out_size, void* d_ws, size_t ws_size,
                              hipStream_t stream) {
  const float* q   = (const float*)d_in[0];
  const float* k   = (const float*)d_in[1];
  const float* v   = (const float*)d_in[2];
  const float* W_q = (const float*)d_in[3];
  const float* b_q = (const float*)d_in[4];
  const float* W_k = (const float*)d_in[5];
  const float* b_k = (const float*)d_in[6];
  const float* W_v = (const float*)d_in[7];
  const float* b_v = (const float*)d_in[8];
  const float* W_o = (const float*)d_in[9];
  const float* b_o = (const float*)d_in[10];

  const size_t SD  = (size_t)BATCH * SEQ * DM;          // 8,388,608 elems
  const size_t SDB = SD * 2;                            // bytes per bf16 buffer
  const size_t D2  = (size_t)DM * DM;                   // 1,048,576 elems
  if (ws_size < 5 * SDB + D2 * 2) return;               // ~86 MB

  char* base = (char*)d_ws;
  unsigned short* B0 = (unsigned short*)(base);             // XQ -> AO
  unsigned short* B1 = (unsigned short*)(base + 1 * SDB);   // XK -> Vt
  unsigned short* B2 = (unsigned short*)(base + 2 * SDB);   // XV
  unsigned short* B3 = (unsigned short*)(base + 3 * SDB);   // Qp
  unsigned short* B4 = (unsigned short*)(base + 4 * SDB);   // Kp
  unsigned short* Wb = (unsigned short*)(base + 5 * SDB);   // Wo bf16 (2MB)

  // bf16 Wq/Wk/Wv parked in d_out's front 6MB (fully overwritten by O-GEMM later)
  unsigned short* dW0 = (unsigned short*)d_out;             // Wq
  unsigned short* dW1 = dW0 + D2;                           // Wk
  unsigned short* dW2 = dW0 + 2 * D2;                       // Wv

  const int nSD4 = (int)(SD / 4), nD24 = (int)(D2 / 4);
  const dim3 blk(256);

  cvt3_k<<<dim3(nSD4 / 256, 3), blk, 0, stream>>>(q, k, v, B0, B1, B2, nSD4);
  cvt4_k<<<dim3(nD24 / 256, 4), blk, 0, stream>>>(W_q, W_k, W_v, W_o, dW0, dW1, dW2, Wb, nD24);
  // Q and K projections (one dispatch)
  gemm_qk<<<dim3(DM / 128, (BATCH * SEQ) / 128, 2), blk, 0, stream>>>(
      B0, B1, dW0, dW1, b_q, b_k, B3, B4, BATCH * SEQ, DM, DM);
  // V projection, transposed output: Vt[d, b*S+s] = (W_v XV^T)[d, i] + b_v[d]
  gemm_bt<true, false><<<dim3((BATCH * SEQ) / 128, DM / 128), blk, 0, stream>>>(
      dW2, B2, b_v, B1, DM, BATCH * SEQ, DM);
  // fused attention
  attn_k<<<dim3(16 * NH * BATCH), blk, 0, stream>>>(B3, B4, B1, B0);
  // output projection -> fp32
  gemm_bt<false, true><<<dim3(DM / 128, (BATCH * SEQ) / 128), blk, 0, stream>>>(
      B0, Wb, b_o, d_out, BATCH * SEQ, DM, DM);
}